// Round 12
// baseline (61.843 us; speedup 1.0000x reference)
//
#include <hip/hip_runtime.h>

// Problem constants (B=1): inputs (N=32768, D=1024) f32, tag_to_token (T=128, N) f32,
// gat_mask (T, T) i32. Output (T, D) f32.
#define NTOK 32768
#define NTAG 128
#define DDIM 1024
#define TPB 32  // tokens per fused block

// ws layout:
//   P   : 524288 B (unscaled per-tag sums)
//   cnt : 512 B
//   Wa  : 65536 B (128x128 matrix buffer, ping)
//   Wb  : 65536 B (128x128 matrix buffer, pong; ends as final A)

// ---------------------------------------------------------------------------
// Kernel 0 (k_rt): zero P/cnt + build the 8 group matrices (16-row back-sub)
// into Wa. deduce_child(gm) == gm for ANY input (reference inner loop is
// provably a no-op). Group g's rows are exact linear functionals of the
// pre-group state:
//   rt_j = gm_j masked to t outside (j, 16g+16)
//        + sum_{k in group, k>j} gm_j[k] * rt_k     (exact ints in f32)
// Rows outside any group's 16 nontrivial rows are implicit identity — the
// full Wa holds all 128 nontrivial rows (every row belongs to one group).
// ---------------------------------------------------------------------------
__global__ __launch_bounds__(256) void k_rt(const int* __restrict__ gm,
                                            float* __restrict__ P,
                                            int* __restrict__ cnt,
                                            float* __restrict__ Wa) {
    __shared__ float rt[16][NTAG];
    __shared__ float gblk[16][16];
    const int tid = threadIdx.x;
    const int b = blockIdx.x;

    // Zero P (32768 float4 over 4096 threads -> 8 each) and cnt.
    float4* P4 = reinterpret_cast<float4*>(P);
#pragma unroll
    for (int q = 0; q < 8; ++q)
        P4[q * 4096 + b * 256 + tid] = make_float4(0.f, 0.f, 0.f, 0.f);
    if (b == 0 && tid < NTAG) cnt[tid] = 0;

    if (b >= 8) return;
    const int g0 = b * 16;
    const int t = tid & 127;  // column (tids 128..255 duplicate: benign)

    gblk[tid >> 4][tid & 15] =
        (float)(gm[(g0 + (tid >> 4)) * NTAG + g0 + (tid & 15)] != 0);
    float grows[16];
#pragma unroll
    for (int jj = 0; jj < 16; ++jj)
        grows[jj] = (float)(gm[(g0 + jj) * NTAG + t] != 0);
    __syncthreads();

#pragma unroll
    for (int jj = 15; jj >= 0; --jj) {
        const int j = g0 + jj;
        float acc = (t > j && t < g0 + 16) ? 0.f : grows[jj];
        for (int k = jj + 1; k < 16; ++k) acc += gblk[jj][k] * rt[k][t];
        rt[jj][t] = acc;
        __syncthreads();
    }

#pragma unroll
    for (int jj = 0; jj < 16; ++jj) Wa[(g0 + jj) * NTAG + t] = rt[jj][t];
}

// ---------------------------------------------------------------------------
// Kernel k_comb<S>: one tree-combine level. Pairs of adjacent S-row blocks:
// lo rows [base, base+S) get hi-span [base+S, base+2S) substituted:
//   out[i][c] = in[i][c] * (c not in hi-span)
//             + sum_{t in hi-span} in[i][base+S+t] * in[base+S+t][c]
// hi rows copied through. A = ((G0G1)(G2G3))((G4G5)(G6G7)) by associativity
// (no reordering of the group product). All values exact path counts.
// Grid = 16 blocks = (pairs) x (column chunks); 512 outputs per block.
// ---------------------------------------------------------------------------
template <int S>
__global__ __launch_bounds__(256) void k_comb(const float* __restrict__ Win,
                                              float* __restrict__ Wout) {
    constexpr int NP = 64 / S;    // pairs: 4, 2, 1
    constexpr int CPP = 16 / NP;  // col chunks per pair: 4, 8, 16
    constexpr int CW = 128 / CPP; // chunk width: 32, 16, 8
    __shared__ float hi[S * CW];        // hi rows x chunk cols (2 KB)
    __shared__ float co[S * (S + 1)];   // lo-row coeffs over hi-span (padded)
    const int tid = threadIdx.x;
    const int pair = blockIdx.x / CPP;
    const int chunk = blockIdx.x % CPP;
    const int base = pair * 2 * S;
    const int c0 = chunk * CW;

    for (int q = tid; q < S * CW; q += 256)
        hi[q] = Win[(base + S + q / CW) * NTAG + c0 + (q % CW)];
    for (int q = tid; q < S * S; q += 256)
        co[(q / S) * (S + 1) + (q % S)] = Win[(base + q / S) * NTAG + base + S + (q % S)];
    __syncthreads();

    for (int q = tid; q < S * CW; q += 256) {
        const int rl = q / CW, c = q % CW;
        const int i = base + rl, cc = c0 + c;
        const bool inhi = (cc >= base + S) && (cc < base + 2 * S);
        float acc = inhi ? 0.f : Win[i * NTAG + cc];
#pragma unroll
        for (int t = 0; t < S; ++t)
            acc += co[rl * (S + 1) + t] * hi[t * CW + c];
        Wout[i * NTAG + cc] = acc;
        Wout[(base + S + rl) * NTAG + cc] = hi[rl * CW + c];  // hi row copy
    }
}

// ---------------------------------------------------------------------------
// Kernel 1: fused tag-scan + segmented sum (unchanged since R6, ~15.5us).
// Math fact: deduce_direct_string's temp[i][n] is 1 iff i is the LAST
// covering tag of n (for ANY 0/1 coverage), so normalized t2t is one-hot per
// token / cnt[tag] -> the big matmul is a segmented sum into P[tag].
// ---------------------------------------------------------------------------
__global__ __launch_bounds__(256) void k_fused(const float* __restrict__ inp,
                                               const float* __restrict__ t2t,
                                               float* __restrict__ P,
                                               int* __restrict__ cnt) {
    __shared__ int part[8][TPB];
    __shared__ int tags[TPB];
    const int tid = threadIdx.x;
    const int n0 = blockIdx.x * TPB;

    {
        const int c = tid >> 5;
        const int n = tid & 31;
        int m = -1;
#pragma unroll
        for (int j = 0; j < 16; ++j) {
            const int r = c * 16 + j;
            if (t2t[(size_t)r * NTOK + n0 + n] > 0.f) m = r;
        }
        part[c][n] = m;
    }
    __syncthreads();
    if (tid < TPB) {
        int m = -1;
#pragma unroll
        for (int cc = 0; cc < 8; ++cc) m = max(m, part[cc][tid]);
        tags[tid] = m;
    }
    __syncthreads();

    const int col = tid * 4;
    const float4* src = reinterpret_cast<const float4*>(inp) + (size_t)n0 * 256 + tid;

    float4 acc = make_float4(0.f, 0.f, 0.f, 0.f);
    int cur = tags[0];
    int runlen = 0;

#pragma unroll
    for (int half = 0; half < 2; ++half) {
        float4 v[16];
#pragma unroll
        for (int k = 0; k < 16; ++k)
            v[k] = src[(size_t)(half * 16 + k) * 256];
#pragma unroll
        for (int k = 0; k < 16; ++k) {
            const int tg = tags[half * 16 + k];
            if (tg != cur) {
                if (cur >= 0) {
                    float* p = P + (size_t)cur * DDIM + col;
                    atomicAdd(p + 0, acc.x);
                    atomicAdd(p + 1, acc.y);
                    atomicAdd(p + 2, acc.z);
                    atomicAdd(p + 3, acc.w);
                    if (tid == 0) atomicAdd(&cnt[cur], runlen);
                }
                acc = make_float4(0.f, 0.f, 0.f, 0.f);
                cur = tg;
                runlen = 0;
            }
            if (tg >= 0) {
                acc.x += v[k].x;
                acc.y += v[k].y;
                acc.z += v[k].z;
                acc.w += v[k].w;
                ++runlen;
            }
        }
    }
    if (cur >= 0) {
        float* p = P + (size_t)cur * DDIM + col;
        atomicAdd(p + 0, acc.x);
        atomicAdd(p + 1, acc.y);
        atomicAdd(p + 2, acc.z);
        atomicAdd(p + 3, acc.w);
        if (tid == 0) atomicAdd(&cnt[cur], runlen);
    }
}

// ---------------------------------------------------------------------------
// Kernel 2 (k_applyA): out = A * p, p[t] = P[t]/cnt[t]. Dense 128x128 by
// 128x1024, fully parallel (NO serial chain, NO cross-lane, NO shared-o LDS
// amplification). 32 blocks x 32 cols; thread = 4x4 register tile (rows
// 4*(tid>>3), cols 4*(tid&7)). A rows stream from L2 (64KB, hot) straight
// into registers: 8 loads feed 64 fma. p staged once per block (16 KB LDS).
// ---------------------------------------------------------------------------
__device__ __forceinline__ void fma4(float4& a, float w, const float4& p) {
    a.x = fmaf(w, p.x, a.x);
    a.y = fmaf(w, p.y, a.y);
    a.z = fmaf(w, p.z, a.z);
    a.w = fmaf(w, p.w, a.w);
}

__global__ __launch_bounds__(256) void k_applyA(const float* __restrict__ P,
                                                const float* __restrict__ A,
                                                const int* __restrict__ cnt,
                                                float* __restrict__ out) {
    __shared__ float pl[NTAG * 32];  // p[t][c-chunk], 16 KB
    __shared__ float inv[NTAG];
    const int tid = threadIdx.x;
    const int c0 = blockIdx.x * 32;

    if (tid < NTAG) inv[tid] = 1.0f / (float)cnt[tid];
    __syncthreads();
    for (int q = tid; q < NTAG * 32; q += 256) {
        const int t = q >> 5, c = q & 31;
        pl[q] = P[(size_t)t * DDIM + c0 + c] * inv[t];
    }
    __syncthreads();

    const int i0 = (tid >> 3) * 4;  // 4 output rows
    const int c4 = (tid & 7) * 4;   // 4 output cols (within chunk)
    const float* a0 = A + (size_t)(i0 + 0) * NTAG;
    const float* a1 = A + (size_t)(i0 + 1) * NTAG;
    const float* a2 = A + (size_t)(i0 + 2) * NTAG;
    const float* a3 = A + (size_t)(i0 + 3) * NTAG;
    float4 acc0 = make_float4(0.f, 0.f, 0.f, 0.f);
    float4 acc1 = acc0, acc2 = acc0, acc3 = acc0;

#pragma unroll 8
    for (int t = 0; t < NTAG; t += 4) {
        const float4 w0 = *reinterpret_cast<const float4*>(a0 + t);
        const float4 w1 = *reinterpret_cast<const float4*>(a1 + t);
        const float4 w2 = *reinterpret_cast<const float4*>(a2 + t);
        const float4 w3 = *reinterpret_cast<const float4*>(a3 + t);
        const float4 p0 = *reinterpret_cast<const float4*>(&pl[(t + 0) * 32 + c4]);
        const float4 p1 = *reinterpret_cast<const float4*>(&pl[(t + 1) * 32 + c4]);
        const float4 p2 = *reinterpret_cast<const float4*>(&pl[(t + 2) * 32 + c4]);
        const float4 p3 = *reinterpret_cast<const float4*>(&pl[(t + 3) * 32 + c4]);
        fma4(acc0, w0.x, p0); fma4(acc0, w0.y, p1); fma4(acc0, w0.z, p2); fma4(acc0, w0.w, p3);
        fma4(acc1, w1.x, p0); fma4(acc1, w1.y, p1); fma4(acc1, w1.z, p2); fma4(acc1, w1.w, p3);
        fma4(acc2, w2.x, p0); fma4(acc2, w2.y, p1); fma4(acc2, w2.z, p2); fma4(acc2, w2.w, p3);
        fma4(acc3, w3.x, p0); fma4(acc3, w3.y, p1); fma4(acc3, w3.z, p2); fma4(acc3, w3.w, p3);
    }

    *reinterpret_cast<float4*>(out + (size_t)(i0 + 0) * DDIM + c0 + c4) = acc0;
    *reinterpret_cast<float4*>(out + (size_t)(i0 + 1) * DDIM + c0 + c4) = acc1;
    *reinterpret_cast<float4*>(out + (size_t)(i0 + 2) * DDIM + c0 + c4) = acc2;
    *reinterpret_cast<float4*>(out + (size_t)(i0 + 3) * DDIM + c0 + c4) = acc3;
}

// ---------------------------------------------------------------------------
extern "C" void kernel_launch(void* const* d_in, const int* in_sizes, int n_in,
                              void* d_out, int out_size, void* d_ws, size_t ws_size,
                              hipStream_t stream) {
    const float* inp = (const float*)d_in[0];  // (N, D)
    const float* t2t = (const float*)d_in[1];  // (T, N)
    const int* gm = (const int*)d_in[2];       // (T, T)
    float* out = (float*)d_out;                // (T, D)

    char* ws = (char*)d_ws;
    float* P = (float*)ws;                       // 524288 B
    int* cnt = (int*)(ws + 524288);              // 512 B
    float* Wa = (float*)(ws + 524800);           // 65536 B
    float* Wb = (float*)(ws + 524800 + 65536);   // 65536 B

    k_rt<<<16, 256, 0, stream>>>(gm, P, cnt, Wa);       // RT16 -> Wa
    k_comb<16><<<16, 256, 0, stream>>>(Wa, Wb);         // pairs of 16 -> Wb
    k_comb<32><<<16, 256, 0, stream>>>(Wb, Wa);         // pairs of 32 -> Wa
    k_comb<64><<<16, 256, 0, stream>>>(Wa, Wb);         // final A -> Wb
    k_fused<<<NTOK / TPB, 256, 0, stream>>>(inp, t2t, P, cnt);
    k_applyA<<<32, 256, 0, stream>>>(P, Wb, cnt, out);
}